// Round 5
// baseline (334.776 us; speedup 1.0000x reference)
//
#include <hip/hip_runtime.h>
#include <hip/hip_bf16.h>

#define BB 4
#define SS 1024
#define PP 1024
#define EE 1024
#define HH 16
#define DD 64
#define NS 2048          // P + S
#define E3 3072
#define VOFF 8388608     // element offset of V section in present [2,B,H,NS,D]
#define VPAST 4194304    // element offset of V section in layer_past [2,B,H,P,D]

typedef __attribute__((ext_vector_type(8))) short short8;
typedef __attribute__((ext_vector_type(4))) float floatx4;
typedef __attribute__((ext_vector_type(16))) float floatx16;
typedef __attribute__((ext_vector_type(4))) unsigned uintx4;

__device__ __forceinline__ short f2bf(float f) {
    return (short)(__bfloat16_as_ushort(__float2bfloat16(f)));
}

__device__ __forceinline__ unsigned cvtpk(float lo, float hi) {
    unsigned r;
    asm("v_cvt_pk_bf16_f32 %0, %1, %2" : "=v"(r) : "v"(lo), "v"(hi));
    return r;
}

__device__ __forceinline__ void plswap(unsigned &a, unsigned &b) {
    asm("v_permlane32_swap_b32 %0, %1" : "+v"(a), "+v"(b));
}

// async global->LDS, 16B per lane; lds ptr must be wave-uniform (HW: base + lane*16)
__device__ __forceinline__ void gload16(const void* g, void* l) {
    __builtin_amdgcn_global_load_lds(
        (const __attribute__((address_space(1))) void*)g,
        (__attribute__((address_space(3))) void*)l, 16, 0, 0);
}

// ---- cvt: x -> xb ; past K -> kbp bf16 ; past K/V -> present f32 past-slots ----
__global__ __launch_bounds__(256) void cvt_copy_k(
    const float* __restrict__ x, const float* __restrict__ past,
    short* __restrict__ xb, short* __restrict__ kbp,
    float* __restrict__ present)
{
    size_t e0 = ((size_t)blockIdx.x * 256 + threadIdx.x) * 8;
    if (e0 < 4194304) {                       // x [4096][1024]
        float4 a0 = *(const float4*)(x + e0);
        float4 a1 = *(const float4*)(x + e0 + 4);
        short8 s;
        s[0] = f2bf(a0.x); s[1] = f2bf(a0.y); s[2] = f2bf(a0.z); s[3] = f2bf(a0.w);
        s[4] = f2bf(a1.x); s[5] = f2bf(a1.y); s[6] = f2bf(a1.z); s[7] = f2bf(a1.w);
        *(short8*)(xb + e0) = s;
    } else {
        size_t r = e0 - 4194304;
        int sec = (r >= 4194304);             // 0: K, 1: V
        if (sec) r -= 4194304;
        const float* src = past + (sec ? VPAST : 0) + r;
        int row = (int)(r >> 6);              // bh*1024 + t
        int bh = row >> 10, t = row & 1023, d = (int)(r & 63);
        size_t off = ((size_t)bh * NS + t) * DD + d;
        float4 a0 = *(const float4*)src;
        float4 a1 = *(const float4*)(src + 4);
        if (!sec) {                           // K: also bf16 copy (natural layout)
            short8 s;
            s[0] = f2bf(a0.x); s[1] = f2bf(a0.y); s[2] = f2bf(a0.z); s[3] = f2bf(a0.w);
            s[4] = f2bf(a1.x); s[5] = f2bf(a1.y); s[6] = f2bf(a1.z); s[7] = f2bf(a1.w);
            *(short8*)(kbp + off) = s;
        }
        float* pd = present + (sec ? VOFF : 0) + off;
        *(float4*)(pd)     = a0;
        *(float4*)(pd + 4) = a1;
    }
}

// --- transpose+cvt 64x64 f32 tiles -> bf16: w_attn^T, w_proj^T, and past-V^T ([bh][d][t]) ---
__global__ __launch_bounds__(256) void wtrans_k(
    const float* __restrict__ wa, const float* __restrict__ wp,
    const float* __restrict__ past,
    short* __restrict__ wab, short* __restrict__ wpb, short* __restrict__ vtb)
{
    __shared__ short Ts[64][72];
    int bid = blockIdx.x;
    const float* s0; short* d0p; int RS, DS2;
    if (bid < 768) {                          // w_attn [1024,3072] -> wab [3072][1024]
        int k0 = (bid & 15) * 64, n0 = (bid >> 4) * 64;
        s0 = wa + (size_t)k0 * E3 + n0; RS = E3;
        d0p = wab + (size_t)n0 * EE + k0; DS2 = EE;
    } else if (bid < 1024) {                  // w_proj [1024,1024] -> wpb [1024][1024]
        int b2 = bid - 768;
        int k0 = (b2 & 15) * 64, n0 = (b2 >> 4) * 64;
        s0 = wp + (size_t)k0 * EE + n0; RS = EE;
        d0p = wpb + (size_t)n0 * EE + k0; DS2 = EE;
    } else {                                  // past V [bh][t][d] -> vtb [bh][d][t]
        int b2 = bid - 1024;
        int bh = b2 >> 4, t0 = (b2 & 15) * 64;
        s0 = past + VPAST + ((size_t)bh * PP + t0) * 64; RS = 64;
        d0p = vtb + (size_t)bh * 64 * NS + t0; DS2 = NS;
    }
    int tid = threadIdx.x;
    int r = tid >> 2, c = (tid & 3) * 16;
    const float* s = s0 + (size_t)r * RS + c;
    float4 a0 = *(const float4*)(s);
    float4 a1 = *(const float4*)(s + 4);
    float4 a2 = *(const float4*)(s + 8);
    float4 a3 = *(const float4*)(s + 12);
    Ts[c +  0][r] = f2bf(a0.x); Ts[c +  1][r] = f2bf(a0.y);
    Ts[c +  2][r] = f2bf(a0.z); Ts[c +  3][r] = f2bf(a0.w);
    Ts[c +  4][r] = f2bf(a1.x); Ts[c +  5][r] = f2bf(a1.y);
    Ts[c +  6][r] = f2bf(a1.z); Ts[c +  7][r] = f2bf(a1.w);
    Ts[c +  8][r] = f2bf(a2.x); Ts[c +  9][r] = f2bf(a2.y);
    Ts[c + 10][r] = f2bf(a2.z); Ts[c + 11][r] = f2bf(a2.w);
    Ts[c + 12][r] = f2bf(a3.x); Ts[c + 13][r] = f2bf(a3.y);
    Ts[c + 14][r] = f2bf(a3.z); Ts[c + 15][r] = f2bf(a3.w);
    __syncthreads();
    int n = tid >> 2, kc = (tid & 3) * 16;
    short8 v0 = *(const short8*)&Ts[n][kc];
    short8 v1 = *(const short8*)&Ts[n][kc + 8];
    short* d = d0p + (size_t)n * DS2 + kc;
    *(short8*)d = v0;
    *(short8*)(d + 8) = v1;
}

// ------- GEMM: C = A[M,1024] @ Bt[N,1024]^T + bias. 2-phase LDS double-buffer (T3-min) ----
template<int MODE, int NT>
__global__ __launch_bounds__(256) void gemm_bt_k(
    const short* __restrict__ A,
    const short* __restrict__ Bt,
    const float* __restrict__ bias,
    float* __restrict__ outf,
    short* __restrict__ qb, short* __restrict__ kbp, short* __restrict__ vtb,
    float* __restrict__ present,
    int N)
{
    constexpr int MR = (NT == 128) ? 4 : 2;      // per-wave m fragment reps
    __shared__ __align__(16) short As[2][128 * 32];
    __shared__ __align__(16) short Bs[2][NT * 32];
    int tid = threadIdx.x;
    int wave = tid >> 6, lane = tid & 63;
    int fr = lane & 15, quad = lane >> 4;
    int wm = (NT == 128) ? (wave >> 1) : wave;
    int wn = (NT == 128) ? (wave & 1) : 0;
    // XCD-chunked bijective swizzle (nwg % 8 == 0)
    int hw = blockIdx.y * gridDim.x + blockIdx.x;
    int nwg = gridDim.x * gridDim.y;
    int work = (hw & 7) * (nwg >> 3) + (hw >> 3);
    int bx = work / gridDim.y, by = work - bx * gridDim.y;
    int m0 = bx * 128, n0 = by * NT;

    floatx4 acc[MR][4];
#pragma unroll
    for (int m = 0; m < MR; ++m)
#pragma unroll
        for (int n = 0; n < 4; ++n) acc[m][n] = (floatx4){0.f, 0.f, 0.f, 0.f};

    auto STAGE = [&](int k0, int buf) {
#pragma unroll
        for (int p = 0; p < 2; ++p) {
            int idx = p * 256 + tid;
            int row = idx >> 2, ch = idx & 3;
            gload16(A + (size_t)(m0 + row) * 1024 + k0 + ch * 8,
                    &As[buf][(p * 256 + wave * 64) * 8]);
        }
#pragma unroll
        for (int p = 0; p < NT / 64; ++p) {
            int idx = p * 256 + tid;
            int row = idx >> 2, ch = idx & 3;
            gload16(Bt + (size_t)(n0 + row) * 1024 + k0 + ch * 8,
                    &Bs[buf][(p * 256 + wave * 64) * 8]);
        }
    };

    STAGE(0, 0);
    __syncthreads();                       // drains vmcnt(0): tile 0 ready
    for (int k0 = 0; k0 < 1024; k0 += 32) {
        int cur = (k0 >> 5) & 1;
        if (k0 + 32 < 1024) STAGE(k0 + 32, cur ^ 1);   // issue next tile BEFORE compute
        short8 af[MR], bf[4];
#pragma unroll
        for (int m = 0; m < MR; ++m)
            af[m] = *(const short8*)(&As[cur][(wm * (MR * 16) + m * 16 + fr) * 32 + quad * 8]);
#pragma unroll
        for (int n = 0; n < 4; ++n)
            bf[n] = *(const short8*)(&Bs[cur][(wn * 64 + n * 16 + fr) * 32 + quad * 8]);
#pragma unroll
        for (int m = 0; m < MR; ++m)
#pragma unroll
            for (int n = 0; n < 4; ++n)
                acc[m][n] = __builtin_amdgcn_mfma_f32_16x16x32_bf16(af[m], bf[n], acc[m][n], 0, 0, 0);
        __syncthreads();                   // one vmcnt(0)+barrier per K-step, AFTER compute
    }
#pragma unroll
    for (int n = 0; n < 4; ++n) {
        int gc = n0 + wn * 64 + n * 16 + fr;
        float bv = bias[gc];
#pragma unroll
        for (int m = 0; m < MR; ++m) {
#pragma unroll
            for (int r = 0; r < 4; ++r) {
                int gr = m0 + wm * (MR * 16) + m * 16 + quad * 4 + r;
                float val = acc[m][n][r] + bv;
                if (MODE == 1) {
                    outf[(size_t)gr * N + gc] = val;
                } else {
                    int sec = gc >> 10, h = (gc >> 6) & 15, d = gc & 63;
                    int b = gr >> 10, sq = gr & 1023;
                    size_t bh = (size_t)(b * HH + h);
                    if (sec == 0) {
                        // fold 1/sqrt(D) * log2(e): S comes out of QK^T in log2 domain
                        qb[(bh * SS + sq) * DD + d] = f2bf(val * 0.18033688f);
                    } else {
                        size_t off = (bh * NS + PP + sq) * DD + d;
                        if (sec == 1) {
                            present[off] = val;
                            kbp[off] = f2bf(val);
                        } else {
                            present[VOFF + off] = val;
                            vtb[(bh * 64 + d) * NS + PP + sq] = f2bf(val);  // transposed
                        }
                    }
                }
            }
        }
    }
}

// -------- flash attention: barrier-free waves, K/V^T direct-from-global MFMA frags --------
// 512 thr = 8 waves: wave = (qt 0..3)*2 + sp.  Wave handles 32 q rows (q = qb0+qt*32+qcol),
// key chunks c = sp, sp+2, ... (32 keys each).  K [bh][t][d] natural; V stored TRANSPOSED
// [bh][d][t] so both QK^T and PV A-fragments are coalesced 16B global loads. No LDS/barriers
// in the loop (K/V is XCD-L2-resident: 4 MB per 8 bh). sp-pair merges via LDS at the end.
__global__ __launch_bounds__(512) void flash_attn_k(
    const short* __restrict__ qb, const short* __restrict__ kbp,
    const short* __restrict__ vtb, short* __restrict__ ab)
{
    __shared__ __align__(16) short smem[16384];  // 32 KB, used only in the final merge

    int tid = threadIdx.x;
    int wave = tid >> 6, lane = tid & 63;
    int qcol = lane & 31, hi = lane >> 5;
    int qt = wave >> 1, sp = wave & 1;

    // XCD-chunked swizzle: XCD n -> bh in [n*8, n*8+8)
    int bid = blockIdx.x;
    int work = (bid & 7) * 64 + (bid >> 3);
    int bh = work >> 3;
    int qb0 = (work & 7) * 128;
    int q32 = qb0 + qt * 32;

    // Q^T B-fragments (prescaled by 0.125*log2e -> log2 domain)
    const short* qrow = qb + ((size_t)bh * SS + q32 + qcol) * DD + hi * 8;
    short8 qf[4];
#pragma unroll
    for (int i = 0; i < 4; ++i) qf[i] = *(const short8*)(qrow + i * 16);

    const short* kbase = kbp + (size_t)bh * NS * DD;
    const short* vbase = vtb + (size_t)bh * 64 * NS;

    float m_r = -1e30f, l_r = 0.f;
    floatx16 Oa[2];
#pragma unroll
    for (int dt = 0; dt < 2; ++dt)
#pragma unroll
        for (int r = 0; r < 16; ++r) Oa[dt][r] = 0.f;

    int cmax = 33 + (q32 >> 5);            // chunks of 32 keys, causal bound
    for (int c = sp; c < cmax; c += 2) {
        int t0 = c << 5;
        // ---- direct global A-fragment loads (all 8 independent, issued up front) ----
        const short* kc = kbase + (size_t)(t0 + qcol) * DD + hi * 8;
        short8 kf0 = *(const short8*)(kc);
        short8 kf1 = *(const short8*)(kc + 16);
        short8 kf2 = *(const short8*)(kc + 32);
        short8 kf3 = *(const short8*)(kc + 48);
        const short* vc0 = vbase + (size_t)qcol * NS + t0 + hi * 8;
        const short* vc1 = vbase + (size_t)(32 + qcol) * NS + t0 + hi * 8;
        short8 vf00 = *(const short8*)(vc0);
        short8 vf01 = *(const short8*)(vc0 + 16);
        short8 vf10 = *(const short8*)(vc1);
        short8 vf11 = *(const short8*)(vc1 + 16);
        // ---- S^T[key][q] = K·Q^T (log2 domain) ----
        floatx16 Sa;
#pragma unroll
        for (int r = 0; r < 16; ++r) Sa[r] = 0.f;
        Sa = __builtin_amdgcn_mfma_f32_32x32x16_bf16(kf0, qf[0], Sa, 0, 0, 0);
        Sa = __builtin_amdgcn_mfma_f32_32x32x16_bf16(kf1, qf[1], Sa, 0, 0, 0);
        Sa = __builtin_amdgcn_mfma_f32_32x32x16_bf16(kf2, qf[2], Sa, 0, 0, 0);
        Sa = __builtin_amdgcn_mfma_f32_32x32x16_bf16(kf3, qf[3], Sa, 0, 0, 0);
        // causal mask (near-diagonal chunks only)
        if (t0 + 31 > PP + q32) {
            int qa = PP + q32 + qcol;
#pragma unroll
            for (int r = 0; r < 16; ++r) {
                int ka = t0 + (r & 3) + 8 * (r >> 2) + 4 * hi;
                if (ka > qa) Sa[r] = -1e30f;
            }
        }
        // ---- in-register online softmax; defer-max (THR = 8 nats = 11.54 log2) ----
        float mx0 = fmaxf(Sa[0], Sa[1]),  mx1 = fmaxf(Sa[2], Sa[3]);
        float mx2 = fmaxf(Sa[4], Sa[5]),  mx3 = fmaxf(Sa[6], Sa[7]);
        mx0 = fmaxf(mx0, fmaxf(Sa[8], Sa[9]));
        mx1 = fmaxf(mx1, fmaxf(Sa[10], Sa[11]));
        mx2 = fmaxf(mx2, fmaxf(Sa[12], Sa[13]));
        mx3 = fmaxf(mx3, fmaxf(Sa[14], Sa[15]));
        float mx = fmaxf(fmaxf(mx0, mx1), fmaxf(mx2, mx3));
        mx = fmaxf(mx, __shfl_xor(mx, 32, 64));
        if (!__all(mx <= m_r + 11.5416f)) {
            float mnew = fmaxf(m_r, mx);
            float al = exp2f(m_r - mnew);
            l_r *= al;
#pragma unroll
            for (int dt = 0; dt < 2; ++dt)
#pragma unroll
                for (int r = 0; r < 16; ++r) Oa[dt][r] *= al;
            m_r = mnew;
        }
        float s0 = 0.f, s1 = 0.f, s2 = 0.f, s3 = 0.f;
#pragma unroll
        for (int r = 0; r < 16; r += 4) {
            float p0 = exp2f(Sa[r]     - m_r);
            float p1 = exp2f(Sa[r + 1] - m_r);
            float p2 = exp2f(Sa[r + 2] - m_r);
            float p3 = exp2f(Sa[r + 3] - m_r);
            Sa[r] = p0; Sa[r + 1] = p1; Sa[r + 2] = p2; Sa[r + 3] = p3;
            s0 += p0; s1 += p1; s2 += p2; s3 += p3;
        }
        float sum = (s0 + s1) + (s2 + s3);
        sum += __shfl_xor(sum, 32, 64);
        l_r += sum;
        // ---- P -> B-operand frags: cvt_pk + permlane32_swap ----
        short8 pfr[2];
        {
            unsigned w0 = cvtpk(Sa[0],  Sa[1]);
            unsigned w2 = cvtpk(Sa[4],  Sa[5]);
            unsigned w1 = cvtpk(Sa[2],  Sa[3]);
            unsigned w3 = cvtpk(Sa[6],  Sa[7]);
            plswap(w0, w2);
            plswap(w1, w3);
            union { uintx4 u; short8 s; } cv0;
            cv0.u = (uintx4){w0, w1, w2, w3};
            pfr[0] = cv0.s;
            unsigned x0 = cvtpk(Sa[8],  Sa[9]);
            unsigned x2 = cvtpk(Sa[12], Sa[13]);
            unsigned x1 = cvtpk(Sa[10], Sa[11]);
            unsigned x3 = cvtpk(Sa[14], Sa[15]);
            plswap(x0, x2);
            plswap(x1, x3);
            union { uintx4 u; short8 s; } cv1;
            cv1.u = (uintx4){x0, x1, x2, x3};
            pfr[1] = cv1.s;
        }
        // ---- O^T += V^T · P^T ----
        Oa[0] = __builtin_amdgcn_mfma_f32_32x32x16_bf16(vf00, pfr[0], Oa[0], 0, 0, 0);
        Oa[0] = __builtin_amdgcn_mfma_f32_32x32x16_bf16(vf01, pfr[1], Oa[0], 0, 0, 0);
        Oa[1] = __builtin_amdgcn_mfma_f32_32x32x16_bf16(vf10, pfr[0], Oa[1], 0, 0, 0);
        Oa[1] = __builtin_amdgcn_mfma_f32_32x32x16_bf16(vf11, pfr[1], Oa[1], 0, 0, 0);
    }

    // ---- merge sp pairs: (m,l,O)_sp0 + (m,l,O)_sp1 via LDS ----
    float* mlf = (float*)smem;                   // [8 waves][32 q][2]
    if (hi == 0) {
        mlf[(wave * 32 + qcol) * 2]     = m_r;
        mlf[(wave * 32 + qcol) * 2 + 1] = l_r;
    }
    __syncthreads();
    float m_o = mlf[((wave ^ 1) * 32 + qcol) * 2];
    float l_o = mlf[((wave ^ 1) * 32 + qcol) * 2 + 1];
    __syncthreads();
    float M = fmaxf(m_r, m_o);
    float sc = exp2f(m_r - M);
    float l_tot = l_r * sc + l_o * exp2f(m_o - M);
    float* Of = (float*)smem;                    // [4 qt][64 d][32 q] f32 = 32 KB
    if (sp == 0) {
#pragma unroll
        for (int dt = 0; dt < 2; ++dt)
#pragma unroll
            for (int r = 0; r < 16; ++r) {
                int d = dt * 32 + (r & 3) + 8 * (r >> 2) + 4 * hi;
                Of[(qt * 64 + d) * 32 + qcol] = Oa[dt][r] * sc;
            }
    }
    __syncthreads();
    if (sp == 1) {
        float inv = 1.f / l_tot;
#pragma unroll
        for (int dt = 0; dt < 2; ++dt)
#pragma unroll
            for (int r = 0; r < 16; ++r) {
                int d = dt * 32 + (r & 3) + 8 * (r >> 2) + 4 * hi;
                Oa[dt][r] = (Of[(qt * 64 + d) * 32 + qcol] + Oa[dt][r] * sc) * inv;
            }
    }
    __syncthreads();
    short* Ot = smem;                            // [4 qt][32 q][72 d] bf16
    if (sp == 1) {
#pragma unroll
        for (int dt = 0; dt < 2; ++dt)
#pragma unroll
            for (int r = 0; r < 16; ++r) {
                int d = dt * 32 + (r & 3) + 8 * (r >> 2) + 4 * hi;
                Ot[(qt * 32 + qcol) * 72 + d] = f2bf(Oa[dt][r]);
            }
    }
    __syncthreads();
    // coalesced store: 512 threads x 32B
    int r2 = tid >> 2;                           // 0..127
    int qgi = r2 >> 5, qi = r2 & 31, doff = (tid & 3) * 16;
    int b = bh >> 4, h = bh & 15;
    int qa = qb0 + qgi * 32 + qi;
    short* dst = ab + ((size_t)(b * SS + qa)) * EE + h * DD + doff;
    const short* srcr = Ot + (qgi * 32 + qi) * 72 + doff;
    *(short8*)(dst)     = *(const short8*)(srcr);
    *(short8*)(dst + 8) = *(const short8*)(srcr + 8);
}

extern "C" void kernel_launch(void* const* d_in, const int* in_sizes, int n_in,
                              void* d_out, int out_size, void* d_ws, size_t ws_size,
                              hipStream_t stream) {
    const float* x      = (const float*)d_in[0];
    const float* past   = (const float*)d_in[1];
    const float* w_attn = (const float*)d_in[2];
    const float* b_attn = (const float*)d_in[3];
    const float* w_proj = (const float*)d_in[4];
    const float* b_proj = (const float*)d_in[5];
    float* out = (float*)d_out;
    float* present = out + (size_t)BB * SS * EE;

    // workspace (bf16 staging), ~67 MiB total
    short* ws  = (short*)d_ws;
    short* xb  = ws;                 // [4096][1024]            4,194,304
    short* wab = xb  + 4194304;      // w_attn^T [3072][1024]   3,145,728
    short* wpb = wab + 3145728;      // w_proj^T [1024][1024]   1,048,576
    short* qb  = wpb + 1048576;      // q [B,H,S,D] prescaled   4,194,304
    short* kbp = qb  + 4194304;      // K [B,H,NS,D]            8,388,608
    short* vtb = kbp + 8388608;      // V^T [B,H,D,NS]          8,388,608
    short* ab  = vtb + 8388608;      // attn out [B,S,E]        4,194,304

    cvt_copy_k<<<6144, 256, 0, stream>>>(x, past, xb, kbp, present);
    wtrans_k<<<2048, 256, 0, stream>>>(w_attn, w_proj, past, wab, wpb, vtb);
    gemm_bt_k<0, 128><<<dim3(32, 24), 256, 0, stream>>>(xb, wab, b_attn, nullptr,
                                                        qb, kbp, vtb, present, E3);
    flash_attn_k<<<512, 512, 0, stream>>>(qb, kbp, vtb, ab);
    gemm_bt_k<1, 64><<<dim3(32, 16), 256, 0, stream>>>(ab, wpb, b_proj, out,
                                                       nullptr, nullptr, nullptr, nullptr, EE);
}

// Round 6
// 311.131 us; speedup vs baseline: 1.0760x; 1.0760x over previous
//
#include <hip/hip_runtime.h>
#include <hip/hip_bf16.h>

#define BB 4
#define SS 1024
#define PP 1024
#define EE 1024
#define HH 16
#define DD 64
#define NS 2048          // P + S
#define E3 3072
#define VOFF 8388608     // element offset of V section in present [2,B,H,NS,D]
#define VPAST 4194304    // element offset of V section in layer_past [2,B,H,P,D]

typedef __attribute__((ext_vector_type(8))) short short8;
typedef __attribute__((ext_vector_type(4))) float floatx4;
typedef __attribute__((ext_vector_type(16))) float floatx16;
typedef __attribute__((ext_vector_type(4))) unsigned uintx4;

__device__ __forceinline__ short f2bf(float f) {
    return (short)(__bfloat16_as_ushort(__float2bfloat16(f)));
}

__device__ __forceinline__ unsigned cvtpk(float lo, float hi) {
    unsigned r;
    asm("v_cvt_pk_bf16_f32 %0, %1, %2" : "=v"(r) : "v"(lo), "v"(hi));
    return r;
}

__device__ __forceinline__ void plswap(unsigned &a, unsigned &b) {
    asm("v_permlane32_swap_b32 %0, %1" : "+v"(a), "+v"(b));
}

// async global->LDS, 16B per lane; lds ptr must be wave-uniform (HW: base + lane*16)
__device__ __forceinline__ void gload16(const void* g, void* l) {
    __builtin_amdgcn_global_load_lds(
        (const __attribute__((address_space(1))) void*)g,
        (__attribute__((address_space(3))) void*)l, 16, 0, 0);
}

// ---- cvt: x -> xb ; past K/V -> kb/vb bf16 AND present f32 past-slots (copy merged) ----
__global__ __launch_bounds__(256) void cvt_copy_k(
    const float* __restrict__ x, const float* __restrict__ past,
    short* __restrict__ xb, short* __restrict__ kbp, short* __restrict__ vbp,
    float* __restrict__ present)
{
    size_t e0 = ((size_t)blockIdx.x * 256 + threadIdx.x) * 8;
    if (e0 < 4194304) {                       // x [4096][1024]
        float4 a0 = *(const float4*)(x + e0);
        float4 a1 = *(const float4*)(x + e0 + 4);
        short8 s;
        s[0] = f2bf(a0.x); s[1] = f2bf(a0.y); s[2] = f2bf(a0.z); s[3] = f2bf(a0.w);
        s[4] = f2bf(a1.x); s[5] = f2bf(a1.y); s[6] = f2bf(a1.z); s[7] = f2bf(a1.w);
        *(short8*)(xb + e0) = s;
    } else {
        size_t r = e0 - 4194304;
        int sec = (r >= 4194304);             // 0: K, 1: V
        if (sec) r -= 4194304;
        const float* src = past + (sec ? VPAST : 0) + r;
        int row = (int)(r >> 6);              // bh*1024 + t
        int bh = row >> 10, t = row & 1023, d = (int)(r & 63);
        size_t off = ((size_t)bh * NS + t) * DD + d;
        float4 a0 = *(const float4*)src;
        float4 a1 = *(const float4*)(src + 4);
        short8 s;
        s[0] = f2bf(a0.x); s[1] = f2bf(a0.y); s[2] = f2bf(a0.z); s[3] = f2bf(a0.w);
        s[4] = f2bf(a1.x); s[5] = f2bf(a1.y); s[6] = f2bf(a1.z); s[7] = f2bf(a1.w);
        *(short8*)((sec ? vbp : kbp) + off) = s;
        float* pd = present + (sec ? VOFF : 0) + off;
        *(float4*)(pd)     = a0;
        *(float4*)(pd + 4) = a1;
    }
}

// ---------------- weight transpose+cvt: W[K,N] f32 -> Wt[N,K] bf16 (64x64 LDS tiles) ----
__global__ __launch_bounds__(256) void wtrans_k(
    const float* __restrict__ wa, const float* __restrict__ wp,
    short* __restrict__ wab, short* __restrict__ wpb)
{
    __shared__ short Ts[64][72];
    int bid = blockIdx.x;
    const float* src; short* dst; int n0, k0, Nsrc;
    if (bid < 768) { k0 = (bid & 15) * 64; n0 = (bid >> 4) * 64; src = wa; dst = wab; Nsrc = E3; }
    else { bid -= 768; k0 = (bid & 15) * 64; n0 = (bid >> 4) * 64; src = wp; dst = wpb; Nsrc = EE; }
    int tid = threadIdx.x;
    int r = tid >> 2, c = (tid & 3) * 16;
    const float* s = src + (size_t)(k0 + r) * Nsrc + n0 + c;
    float4 a0 = *(const float4*)(s);
    float4 a1 = *(const float4*)(s + 4);
    float4 a2 = *(const float4*)(s + 8);
    float4 a3 = *(const float4*)(s + 12);
    Ts[c +  0][r] = f2bf(a0.x); Ts[c +  1][r] = f2bf(a0.y);
    Ts[c +  2][r] = f2bf(a0.z); Ts[c +  3][r] = f2bf(a0.w);
    Ts[c +  4][r] = f2bf(a1.x); Ts[c +  5][r] = f2bf(a1.y);
    Ts[c +  6][r] = f2bf(a1.z); Ts[c +  7][r] = f2bf(a1.w);
    Ts[c +  8][r] = f2bf(a2.x); Ts[c +  9][r] = f2bf(a2.y);
    Ts[c + 10][r] = f2bf(a2.z); Ts[c + 11][r] = f2bf(a2.w);
    Ts[c + 12][r] = f2bf(a3.x); Ts[c + 13][r] = f2bf(a3.y);
    Ts[c + 14][r] = f2bf(a3.z); Ts[c + 15][r] = f2bf(a3.w);
    __syncthreads();
    int n = tid >> 2, kc = (tid & 3) * 16;
    short8 v0 = *(const short8*)&Ts[n][kc];
    short8 v1 = *(const short8*)&Ts[n][kc + 8];
    short* d = dst + (size_t)(n0 + n) * EE + k0 + kc;    // K == 1024 for both weights
    *(short8*)d = v0;
    *(short8*)(d + 8) = v1;
}

// --- GEMM: C = A[M,1024] @ Bt[N,1024]^T + bias. 3-buffer 2-deep prefetch, counted vmcnt ---
template<int MODE, int NT>
__global__ __launch_bounds__(256) void gemm_bt_k(
    const short* __restrict__ A,
    const short* __restrict__ Bt,
    const float* __restrict__ bias,
    float* __restrict__ outf,
    short* __restrict__ qb, short* __restrict__ kbp, short* __restrict__ vbp,
    float* __restrict__ present,
    int N)
{
    constexpr int MR = (NT == 128) ? 4 : 2;      // per-wave m fragment reps
    __shared__ __align__(16) short As[3][128 * 32];
    __shared__ __align__(16) short Bs[3][NT * 32];
    int tid = threadIdx.x;
    int wave = tid >> 6, lane = tid & 63;
    int fr = lane & 15, quad = lane >> 4;
    int wm = (NT == 128) ? (wave >> 1) : wave;
    int wn = (NT == 128) ? (wave & 1) : 0;
    // XCD-chunked bijective swizzle (nwg % 8 == 0)
    int hw = blockIdx.y * gridDim.x + blockIdx.x;
    int nwg = gridDim.x * gridDim.y;
    int work = (hw & 7) * (nwg >> 3) + (hw >> 3);
    int bx = work / gridDim.y, by = work - bx * gridDim.y;
    int m0 = bx * 128, n0 = by * NT;

    floatx4 acc[MR][4];
#pragma unroll
    for (int m = 0; m < MR; ++m)
#pragma unroll
        for (int n = 0; n < 4; ++n) acc[m][n] = (floatx4){0.f, 0.f, 0.f, 0.f};

    auto STAGE = [&](int k0, int buf) {          // NT==128: 4 vmem/thread, NT==64: 3
#pragma unroll
        for (int p = 0; p < 2; ++p) {
            int idx = p * 256 + tid;
            int row = idx >> 2, ch = idx & 3;
            gload16(A + (size_t)(m0 + row) * 1024 + k0 + ch * 8,
                    &As[buf][(p * 256 + wave * 64) * 8]);
        }
#pragma unroll
        for (int p = 0; p < NT / 64; ++p) {
            int idx = p * 256 + tid;
            int row = idx >> 2, ch = idx & 3;
            gload16(Bt + (size_t)(n0 + row) * 1024 + k0 + ch * 8,
                    &Bs[buf][(p * 256 + wave * 64) * 8]);
        }
    };

    STAGE(0, 0);
    STAGE(32, 1);
    for (int t = 0; t < 32; ++t) {
        // counted wait: oldest STAGE (t) retired; STAGE(t+1) stays in flight (T4)
        if (t < 31) {
            if (NT == 128) asm volatile("s_waitcnt vmcnt(4)" ::: "memory");
            else           asm volatile("s_waitcnt vmcnt(3)" ::: "memory");
        } else {
            asm volatile("s_waitcnt vmcnt(0)" ::: "memory");
        }
        __builtin_amdgcn_s_barrier();
        asm volatile("" ::: "memory");
        int cb = t - (t / 3) * 3;                // t % 3
        short8 af[MR], bf[4];
#pragma unroll
        for (int m = 0; m < MR; ++m)
            af[m] = *(const short8*)(&As[cb][(wm * (MR * 16) + m * 16 + fr) * 32 + quad * 8]);
#pragma unroll
        for (int n = 0; n < 4; ++n)
            bf[n] = *(const short8*)(&Bs[cb][(wn * 64 + n * 16 + fr) * 32 + quad * 8]);
        if (t + 2 < 32) {                        // buf (t+2)%3 last read at t-1 -> safe
            int nb = (t + 2) - ((t + 2) / 3) * 3;
            STAGE((t + 2) * 32, nb);
        }
#pragma unroll
        for (int m = 0; m < MR; ++m)
#pragma unroll
            for (int n = 0; n < 4; ++n)
                acc[m][n] = __builtin_amdgcn_mfma_f32_16x16x32_bf16(af[m], bf[n], acc[m][n], 0, 0, 0);
    }
#pragma unroll
    for (int n = 0; n < 4; ++n) {
        int gc = n0 + wn * 64 + n * 16 + fr;
        float bv = bias[gc];
#pragma unroll
        for (int m = 0; m < MR; ++m) {
#pragma unroll
            for (int r = 0; r < 4; ++r) {
                int gr = m0 + wm * (MR * 16) + m * 16 + quad * 4 + r;
                float val = acc[m][n][r] + bv;
                if (MODE == 1) {
                    outf[(size_t)gr * N + gc] = val;
                } else {
                    int sec = gc >> 10, h = (gc >> 6) & 15, d = gc & 63;
                    int b = gr >> 10, sq = gr & 1023;
                    size_t bh = (size_t)(b * HH + h);
                    if (sec == 0) {
                        // fold 1/sqrt(D) * log2(e): S comes out of QK^T in log2 domain
                        qb[(bh * SS + sq) * DD + d] = f2bf(val * 0.18033688f);
                    } else {
                        size_t off = (bh * NS + PP + sq) * DD + d;
                        if (sec == 1) { present[off] = val;        kbp[off] = f2bf(val); }
                        else          { present[VOFF + off] = val; vbp[off] = f2bf(val); }
                    }
                }
            }
        }
    }
}

// ---- flash attention: 64q blocks (2qt x 2sp), LDS-staged K/V dbuf, LPT dispatch order ----
// grid = 1024 (4 blocks/CU). Wave (qt,sp): 32 q rows, computes chunks with parity sp.
// Inner math identical to verified r3/r4 kernels (swapped QK^T, in-reg softmax, log2 domain,
// defer-max, cvt_pk+permlane P-frags). sp pair merges (m,l,O) once at the end.
__global__ __launch_bounds__(256) void flash_attn_k(
    const short* __restrict__ qb, const short* __restrict__ kbp,
    const short* __restrict__ vbp, short* __restrict__ ab)
{
    __shared__ __align__(16) short smem[16384];  // 32 KB: Ks[2][4096] | Vs[2][4096]
    short* Ks = smem;
    short* Vs = smem + 8192;

    int tid = threadIdx.x;
    int wave = tid >> 6, lane = tid & 63;
    int qcol = lane & 31, hi = lane >> 5;
    int qt = wave >> 1, sp = wave & 1;

    // XCD-chunked + LPT: xcd = bid&7 keeps 8 bh per XCD L2; within XCD, longest tiles first
    int bid = blockIdx.x;
    int xcd = bid & 7, s = bid >> 3;             // s in [0,128)
    int j = 15 - (s >> 3);                       // q-tile index, descending work (LPT)
    int bh = xcd * 8 + (s & 7);
    int q0 = j * 64;
    int q32 = q0 + qt * 32;

    // Q^T B-fragments (prescaled by 0.125*log2e -> log2 domain)
    const short* qrow = qb + ((size_t)bh * SS + q32 + qcol) * DD + hi * 8;
    short8 qf[4];
#pragma unroll
    for (int i = 0; i < 4; ++i) qf[i] = *(const short8*)(qrow + i * 16);

    const short* kbase = kbp + (size_t)bh * NS * DD;
    const short* vbase = vbp + (size_t)bh * NS * DD;

    float m_r = -1e30f, l_r = 0.f;
    floatx16 Oa[2];
#pragma unroll
    for (int dt = 0; dt < 2; ++dt)
#pragma unroll
        for (int r = 0; r < 16; ++r) Oa[dt][r] = 0.f;

    int vkey = tid & 63, vd0 = (tid >> 6) * 16;  // V staging: 16 d-rows per thread
    int qminw = PP + q32;
    int qmaxw = qminw + 31;
    int nchunks = 17 + j;                        // chunks of 64 keys

    short8 vs0, vs1;
    auto KISSUE = [&](int cc, int bufi) {
        const short* kc = kbase + (size_t)cc * 64 * DD;
        short* Kd = Ks + bufi * 4096;
#pragma unroll
        for (int p = 0; p < 2; ++p) {
            int idx = p * 256 + tid;
            int row = idx >> 3, ch = idx & 7;
            gload16(kc + row * 64 + ((ch ^ (row & 7)) * 8), Kd + (p * 256 + wave * 64) * 8);
        }
    };
    auto VLOAD = [&](int cc) {
        const short* src = vbase + ((size_t)cc * 64 + vkey) * DD + vd0;
        vs0 = *(const short8*)src;
        vs1 = *(const short8*)(src + 8);
    };
    auto VWRITE = [&](int bufi) {
        short* Vd = Vs + bufi * 4096;
#pragma unroll
        for (int i = 0; i < 8; ++i) {
            int d0i = vd0 + i, d1i = vd0 + 8 + i;
            Vd[d0i * 64 + (((vkey >> 3) ^ (d0i & 7)) << 3) + (vkey & 7)] = vs0[i];
            Vd[d1i * 64 + (((vkey >> 3) ^ (d1i & 7)) << 3) + (vkey & 7)] = vs1[i];
        }
    };

    VLOAD(0); KISSUE(0, 0); VWRITE(0);
    __syncthreads();

    for (int c = 0; c < nchunks; ++c) {
        int t0 = c * 64;
        int cur = c & 1;
        if (c + 1 < nchunks) { VLOAD(c + 1); KISSUE(c + 1, cur ^ 1); }
        if (((c ^ sp) & 1) == 0 && t0 <= qmaxw) {
            const short* Kc = Ks + cur * 4096;
            const short* Vc = Vs + cur * 4096;
            // ---- S^T[key][q] = K·Q^T (log2 domain) ----
            floatx16 Sa[2];
#pragma unroll
            for (int ct = 0; ct < 2; ++ct)
#pragma unroll
                for (int r = 0; r < 16; ++r) Sa[ct][r] = 0.f;
#pragma unroll
            for (int ct = 0; ct < 2; ++ct) {
                int key = ct * 32 + qcol;
                int rbase = key * 64, rx = key & 7;
#pragma unroll
                for (int d0 = 0; d0 < 4; ++d0) {
                    short8 kf = *(const short8*)(Kc + rbase + (((d0 * 2 + hi) ^ rx) * 8));
                    Sa[ct] = __builtin_amdgcn_mfma_f32_32x32x16_bf16(kf, qf[d0], Sa[ct], 0, 0, 0);
                }
            }
            // causal mask (near-diagonal chunks only)
            if (t0 + 63 > qminw) {
                int qa = qminw + qcol;
#pragma unroll
                for (int ct = 0; ct < 2; ++ct)
#pragma unroll
                    for (int r = 0; r < 16; ++r) {
                        int ka = t0 + ct * 32 + (r & 3) + 8 * (r >> 2) + 4 * hi;
                        if (ka > qa) Sa[ct][r] = -1e30f;
                    }
            }
            // ---- in-register online softmax; defer-max (THR = 8 nats = 11.54 log2) ----
            float mx0 = Sa[0][0], mx1 = Sa[0][1], mx2 = Sa[0][2], mx3 = Sa[0][3];
#pragma unroll
            for (int ct = 0; ct < 2; ++ct)
#pragma unroll
                for (int r = (ct ? 0 : 4); r < 16; r += 4) {
                    mx0 = fmaxf(mx0, Sa[ct][r]);
                    mx1 = fmaxf(mx1, Sa[ct][r + 1]);
                    mx2 = fmaxf(mx2, Sa[ct][r + 2]);
                    mx3 = fmaxf(mx3, Sa[ct][r + 3]);
                }
            float mx = fmaxf(fmaxf(mx0, mx1), fmaxf(mx2, mx3));
            mx = fmaxf(mx, __shfl_xor(mx, 32, 64));
            if (!__all(mx <= m_r + 11.5416f)) {
                float mnew = fmaxf(m_r, mx);
                float al = exp2f(m_r - mnew);
                l_r *= al;
#pragma unroll
                for (int dt = 0; dt < 2; ++dt)
#pragma unroll
                    for (int r = 0; r < 16; ++r) Oa[dt][r] *= al;
                m_r = mnew;
            }
            float s0 = 0.f, s1 = 0.f, s2 = 0.f, s3 = 0.f;
#pragma unroll
            for (int ct = 0; ct < 2; ++ct)
#pragma unroll
                for (int r = 0; r < 16; r += 4) {
                    float p0 = exp2f(Sa[ct][r]     - m_r);
                    float p1 = exp2f(Sa[ct][r + 1] - m_r);
                    float p2 = exp2f(Sa[ct][r + 2] - m_r);
                    float p3 = exp2f(Sa[ct][r + 3] - m_r);
                    Sa[ct][r] = p0; Sa[ct][r + 1] = p1; Sa[ct][r + 2] = p2; Sa[ct][r + 3] = p3;
                    s0 += p0; s1 += p1; s2 += p2; s3 += p3;
                }
            float sum = (s0 + s1) + (s2 + s3);
            sum += __shfl_xor(sum, 32, 64);
            l_r += sum;
            // ---- P -> B-operand frags: cvt_pk + permlane32_swap ----
            short8 pfr[2][2];
#pragma unroll
            for (int ct = 0; ct < 2; ++ct) {
                unsigned w0 = cvtpk(Sa[ct][0],  Sa[ct][1]);
                unsigned w2 = cvtpk(Sa[ct][4],  Sa[ct][5]);
                unsigned w1 = cvtpk(Sa[ct][2],  Sa[ct][3]);
                unsigned w3 = cvtpk(Sa[ct][6],  Sa[ct][7]);
                plswap(w0, w2);
                plswap(w1, w3);
                union { uintx4 u; short8 s; } cv0;
                cv0.u = (uintx4){w0, w1, w2, w3};
                pfr[ct][0] = cv0.s;
                unsigned x0 = cvtpk(Sa[ct][8],  Sa[ct][9]);
                unsigned x2 = cvtpk(Sa[ct][12], Sa[ct][13]);
                unsigned x1 = cvtpk(Sa[ct][10], Sa[ct][11]);
                unsigned x3 = cvtpk(Sa[ct][14], Sa[ct][15]);
                plswap(x0, x2);
                plswap(x1, x3);
                union { uintx4 u; short8 s; } cv1;
                cv1.u = (uintx4){x0, x1, x2, x3};
                pfr[ct][1] = cv1.s;
            }
            // ---- O^T += V^T · P^T ----
#pragma unroll
            for (int ct = 0; ct < 2; ++ct)
#pragma unroll
                for (int ks = 0; ks < 2; ++ks) {
                    int chunkb = ct * 4 + ks * 2 + hi;
#pragma unroll
                    for (int dt = 0; dt < 2; ++dt) {
                        int row = dt * 32 + qcol;
                        short8 vf = *(const short8*)(Vc + row * 64 + ((chunkb ^ (row & 7)) << 3));
                        Oa[dt] = __builtin_amdgcn_mfma_f32_32x32x16_bf16(vf, pfr[ct][ks], Oa[dt], 0, 0, 0);
                    }
                }
        }
        if (c + 1 < nchunks) VWRITE(cur ^ 1);
        __syncthreads();
    }

    // ---- merge sp pairs: (m,l,O)_sp0 + (m,l,O)_sp1 via LDS ----
    float* mlf = (float*)smem;                   // [4 waves][32 q][2]
    if (hi == 0) {
        mlf[(wave * 32 + qcol) * 2]     = m_r;
        mlf[(wave * 32 + qcol) * 2 + 1] = l_r;
    }
    __syncthreads();
    float m_o = mlf[((wave ^ 1) * 32 + qcol) * 2];
    float l_o = mlf[((wave ^ 1) * 32 + qcol) * 2 + 1];
    __syncthreads();
    float M = fmaxf(m_r, m_o);
    float sc = exp2f(m_r - M);
    float l_tot = l_r * sc + l_o * exp2f(m_o - M);
    float* Of = (float*)smem;                    // [2 qt][64 d][32 q] f32 = 16 KB
    if (sp == 0) {
#pragma unroll
        for (int dt = 0; dt < 2; ++dt)
#pragma unroll
            for (int r = 0; r < 16; ++r) {
                int d = dt * 32 + (r & 3) + 8 * (r >> 2) + 4 * hi;
                Of[(qt * 64 + d) * 32 + qcol] = Oa[dt][r] * sc;
            }
    }
    __syncthreads();
    if (sp == 1) {
        float inv = 1.f / l_tot;
#pragma unroll
        for (int dt = 0; dt < 2; ++dt)
#pragma unroll
            for (int r = 0; r < 16; ++r) {
                int d = dt * 32 + (r & 3) + 8 * (r >> 2) + 4 * hi;
                Oa[dt][r] = (Of[(qt * 64 + d) * 32 + qcol] + Oa[dt][r] * sc) * inv;
            }
    }
    __syncthreads();
    short* Ot = smem;                            // [2 qt][32 q][72 d] bf16
    if (sp == 1) {
#pragma unroll
        for (int dt = 0; dt < 2; ++dt)
#pragma unroll
            for (int r = 0; r < 16; ++r) {
                int d = dt * 32 + (r & 3) + 8 * (r >> 2) + 4 * hi;
                Ot[(qt * 32 + qcol) * 72 + d] = f2bf(Oa[dt][r]);
            }
    }
    __syncthreads();
    // coalesced store: 256 threads x 32B = 64 rows x 128B
    int r2 = tid >> 2;                           // 0..63
    int qgi = r2 >> 5, qi = r2 & 31, doff = (tid & 3) * 16;
    int b = bh >> 4, h = bh & 15;
    int qa = q0 + qgi * 32 + qi;
    short* dst = ab + ((size_t)(b * SS + qa)) * EE + h * DD + doff;
    const short* srcr = Ot + (qgi * 32 + qi) * 72 + doff;
    *(short8*)(dst)     = *(const short8*)(srcr);
    *(short8*)(dst + 8) = *(const short8*)(srcr + 8);
}

extern "C" void kernel_launch(void* const* d_in, const int* in_sizes, int n_in,
                              void* d_out, int out_size, void* d_ws, size_t ws_size,
                              hipStream_t stream) {
    const float* x      = (const float*)d_in[0];
    const float* past   = (const float*)d_in[1];
    const float* w_attn = (const float*)d_in[2];
    const float* b_attn = (const float*)d_in[3];
    const float* w_proj = (const float*)d_in[4];
    const float* b_proj = (const float*)d_in[5];
    float* out = (float*)d_out;
    float* present = out + (size_t)BB * SS * EE;

    // workspace (bf16 staging), ~67 MiB total
    short* ws  = (short*)d_ws;
    short* xb  = ws;                 // [4096][1024]            4,194,304
    short* wab = xb  + 4194304;      // w_attn^T [3072][1024]   3,145,728
    short* wpb = wab + 3145728;      // w_proj^T [1024][1024]   1,048,576
    short* qb  = wpb + 1048576;      // q [B,H,S,D] prescaled   4,194,304
    short* kbp = qb  + 4194304;      // K [B,H,NS,D]            8,388,608
    short* vbp = kbp + 8388608;      // V [B,H,NS,D]            8,388,608
    short* ab  = vbp + 8388608;      // attn out [B,S,E]        4,194,304

    cvt_copy_k<<<6144, 256, 0, stream>>>(x, past, xb, kbp, vbp, present);
    wtrans_k<<<1024, 256, 0, stream>>>(w_attn, w_proj, wab, wpb);
    gemm_bt_k<0, 128><<<dim3(32, 24), 256, 0, stream>>>(xb, wab, b_attn, nullptr,
                                                        qb, kbp, vbp, present, E3);
    flash_attn_k<<<1024, 256, 0, stream>>>(qb, kbp, vbp, ab);
    gemm_bt_k<1, 64><<<dim3(32, 16), 256, 0, stream>>>(ab, wpb, b_proj, out,
                                                       nullptr, nullptr, nullptr, nullptr, EE);
}

// Round 7
// 265.970 us; speedup vs baseline: 1.2587x; 1.1698x over previous
//
#include <hip/hip_runtime.h>
#include <hip/hip_bf16.h>

#define BB 4
#define SS 1024
#define PP 1024
#define EE 1024
#define HH 16
#define DD 64
#define NS 2048          // P + S
#define E3 3072
#define VOFF 8388608     // element offset of V section in present [2,B,H,NS,D]
#define VPAST 4194304    // element offset of V section in layer_past [2,B,H,P,D]

typedef __attribute__((ext_vector_type(8))) short short8;
typedef __attribute__((ext_vector_type(4))) float floatx4;
typedef __attribute__((ext_vector_type(16))) float floatx16;
typedef __attribute__((ext_vector_type(4))) unsigned uintx4;

// ---- MFMA fragment-major layouts (bf16), per bh ----
// kfrag: [64 c32][4 d0][64 l][8 e]  elem = K[t=c32*32+(l&31)][d=d0*16+(l>>5)*8+e]
// vfrag: [128 c16][2 dt][64 l][8 e] elem = V[t=c16*16+(l>>5)*8+e][d=dt*32+(l&31)]
// qfrag: [32 qt][4 d0][64 l][8 e]   elem = Qs[q=qt*32+(l&31)][d=d0*16+(l>>5)*8+e]

__device__ __forceinline__ short f2bf(float f) {
    return (short)(__bfloat16_as_ushort(__float2bfloat16(f)));
}

__device__ __forceinline__ unsigned cvtpk(float lo, float hi) {
    unsigned r;
    asm("v_cvt_pk_bf16_f32 %0, %1, %2" : "=v"(r) : "v"(lo), "v"(hi));
    return r;
}

__device__ __forceinline__ void plswap(unsigned &a, unsigned &b) {
    asm("v_permlane32_swap_b32 %0, %1" : "+v"(a), "+v"(b));
}

// async global->LDS, 16B per lane; lds ptr must be wave-uniform (HW: base + lane*16)
__device__ __forceinline__ void gload16(const void* g, void* l) {
    __builtin_amdgcn_global_load_lds(
        (const __attribute__((address_space(1))) void*)g,
        (__attribute__((address_space(3))) void*)l, 16, 0, 0);
}

// ---- cvt: x -> xb ; past K/V -> kfrag/vfrag bf16 AND present f32 past-slots ----
__global__ __launch_bounds__(256) void cvt_copy_k(
    const float* __restrict__ x, const float* __restrict__ past,
    short* __restrict__ xb, short* __restrict__ kfrag, short* __restrict__ vfrag,
    float* __restrict__ present)
{
    int bid = blockIdx.x, tid = threadIdx.x;
    if (bid < 2048) {                         // x [4096][1024] -> xb linear
        size_t e0 = ((size_t)bid * 256 + tid) * 8;
        float4 a0 = *(const float4*)(x + e0);
        float4 a1 = *(const float4*)(x + e0 + 4);
        short8 s;
        s[0] = f2bf(a0.x); s[1] = f2bf(a0.y); s[2] = f2bf(a0.z); s[3] = f2bf(a0.w);
        s[4] = f2bf(a1.x); s[5] = f2bf(a1.y); s[6] = f2bf(a1.z); s[7] = f2bf(a1.w);
        *(short8*)(xb + e0) = s;
    } else if (bid < 4096) {                  // past K: frag-major + present f32
        int i = (bid - 2048) * 256 + tid;     // [bh(64)][t(1024)][d8(8)]
        int bh = i >> 13, rem = i & 8191;
        int t = rem >> 3, d8 = rem & 7;
        const float* src = past + (((size_t)bh * 1024 + t) << 6) + d8 * 8;
        float4 a0 = *(const float4*)(src);
        float4 a1 = *(const float4*)(src + 4);
        short8 s;
        s[0] = f2bf(a0.x); s[1] = f2bf(a0.y); s[2] = f2bf(a0.z); s[3] = f2bf(a0.w);
        s[4] = f2bf(a1.x); s[5] = f2bf(a1.y); s[6] = f2bf(a1.z); s[7] = f2bf(a1.w);
        *(short8*)(kfrag + (size_t)bh * 131072 + (t >> 5) * 2048 + (d8 >> 1) * 512
                   + ((t & 31) + (d8 & 1) * 32) * 8) = s;
        float* pd = present + (((size_t)bh * NS + t) << 6) + d8 * 8;
        *(float4*)(pd)     = a0;
        *(float4*)(pd + 4) = a1;
    } else {                                  // past V: frag-major + present f32
        int i = (bid - 4096) * 256 + tid;     // [bh(64)][t8(128)][d(64)]
        int bh = i >> 13, rem = i & 8191;
        int d = rem & 63, t8 = rem >> 6;
        const float* src = past + VPAST + (((size_t)bh * 1024 + t8 * 8) << 6) + d;
        float* pd = present + VOFF + (((size_t)bh * NS + t8 * 8) << 6) + d;
        float v[8];
        short8 s;
#pragma unroll
        for (int j = 0; j < 8; ++j) { v[j] = src[j * 64]; s[j] = f2bf(v[j]); }
        *(short8*)(vfrag + (size_t)bh * 131072 + (t8 >> 1) * 1024 + (d >> 5) * 512
                   + ((d & 31) + (t8 & 1) * 32) * 8) = s;
#pragma unroll
        for (int j = 0; j < 8; ++j) pd[j * 64] = v[j];
    }
}

// ---------------- weight transpose+cvt: W[K,N] f32 -> Wt[N,K] bf16 (64x64 LDS tiles) ----
__global__ __launch_bounds__(256) void wtrans_k(
    const float* __restrict__ wa, const float* __restrict__ wp,
    short* __restrict__ wab, short* __restrict__ wpb)
{
    __shared__ short Ts[64][72];
    int bid = blockIdx.x;
    const float* src; short* dst; int n0, k0, Nsrc;
    if (bid < 768) { k0 = (bid & 15) * 64; n0 = (bid >> 4) * 64; src = wa; dst = wab; Nsrc = E3; }
    else { bid -= 768; k0 = (bid & 15) * 64; n0 = (bid >> 4) * 64; src = wp; dst = wpb; Nsrc = EE; }
    int tid = threadIdx.x;
    int r = tid >> 2, c = (tid & 3) * 16;
    const float* s = src + (size_t)(k0 + r) * Nsrc + n0 + c;
    float4 a0 = *(const float4*)(s);
    float4 a1 = *(const float4*)(s + 4);
    float4 a2 = *(const float4*)(s + 8);
    float4 a3 = *(const float4*)(s + 12);
    Ts[c +  0][r] = f2bf(a0.x); Ts[c +  1][r] = f2bf(a0.y);
    Ts[c +  2][r] = f2bf(a0.z); Ts[c +  3][r] = f2bf(a0.w);
    Ts[c +  4][r] = f2bf(a1.x); Ts[c +  5][r] = f2bf(a1.y);
    Ts[c +  6][r] = f2bf(a1.z); Ts[c +  7][r] = f2bf(a1.w);
    Ts[c +  8][r] = f2bf(a2.x); Ts[c +  9][r] = f2bf(a2.y);
    Ts[c + 10][r] = f2bf(a2.z); Ts[c + 11][r] = f2bf(a2.w);
    Ts[c + 12][r] = f2bf(a3.x); Ts[c + 13][r] = f2bf(a3.y);
    Ts[c + 14][r] = f2bf(a3.z); Ts[c + 15][r] = f2bf(a3.w);
    __syncthreads();
    int n = tid >> 2, kc = (tid & 3) * 16;
    short8 v0 = *(const short8*)&Ts[n][kc];
    short8 v1 = *(const short8*)&Ts[n][kc + 8];
    short* d = dst + (size_t)(n0 + n) * EE + k0 + kc;    // K == 1024 for both weights
    *(short8*)d = v0;
    *(short8*)(d + 8) = v1;
}

// --- GEMM: C = A[M,1024] @ Bt[N,1024]^T + bias. 3-buffer 2-deep prefetch, counted vmcnt ---
template<int MODE, int NT>
__global__ __launch_bounds__(256) void gemm_bt_k(
    const short* __restrict__ A,
    const short* __restrict__ Bt,
    const float* __restrict__ bias,
    float* __restrict__ outf,
    short* __restrict__ qfrag, short* __restrict__ kfrag, short* __restrict__ vfrag,
    float* __restrict__ present,
    int N)
{
    constexpr int MR = (NT == 128) ? 4 : 2;      // per-wave m fragment reps
    __shared__ __align__(16) short As[3][128 * 32];
    __shared__ __align__(16) short Bs[3][NT * 32];
    int tid = threadIdx.x;
    int wave = tid >> 6, lane = tid & 63;
    int fr = lane & 15, quad = lane >> 4;
    int wm = (NT == 128) ? (wave >> 1) : wave;
    int wn = (NT == 128) ? (wave & 1) : 0;
    // XCD-chunked bijective swizzle (nwg % 8 == 0)
    int hw = blockIdx.y * gridDim.x + blockIdx.x;
    int nwg = gridDim.x * gridDim.y;
    int work = (hw & 7) * (nwg >> 3) + (hw >> 3);
    int bx = work / gridDim.y, by = work - bx * gridDim.y;
    int m0 = bx * 128, n0 = by * NT;

    floatx4 acc[MR][4];
#pragma unroll
    for (int m = 0; m < MR; ++m)
#pragma unroll
        for (int n = 0; n < 4; ++n) acc[m][n] = (floatx4){0.f, 0.f, 0.f, 0.f};

    auto STAGE = [&](int k0, int buf) {          // NT==128: 4 vmem/thread, NT==64: 3
#pragma unroll
        for (int p = 0; p < 2; ++p) {
            int idx = p * 256 + tid;
            int row = idx >> 2, ch = idx & 3;
            gload16(A + (size_t)(m0 + row) * 1024 + k0 + ch * 8,
                    &As[buf][(p * 256 + wave * 64) * 8]);
        }
#pragma unroll
        for (int p = 0; p < NT / 64; ++p) {
            int idx = p * 256 + tid;
            int row = idx >> 2, ch = idx & 3;
            gload16(Bt + (size_t)(n0 + row) * 1024 + k0 + ch * 8,
                    &Bs[buf][(p * 256 + wave * 64) * 8]);
        }
    };

    STAGE(0, 0);
    STAGE(32, 1);
    for (int t = 0; t < 32; ++t) {
        // counted wait: oldest STAGE (t) retired; STAGE(t+1) stays in flight (T4)
        if (t < 31) {
            if (NT == 128) asm volatile("s_waitcnt vmcnt(4)" ::: "memory");
            else           asm volatile("s_waitcnt vmcnt(3)" ::: "memory");
        } else {
            asm volatile("s_waitcnt vmcnt(0)" ::: "memory");
        }
        __builtin_amdgcn_s_barrier();
        asm volatile("" ::: "memory");
        int cb = t - (t / 3) * 3;                // t % 3
        short8 af[MR], bf[4];
#pragma unroll
        for (int m = 0; m < MR; ++m)
            af[m] = *(const short8*)(&As[cb][(wm * (MR * 16) + m * 16 + fr) * 32 + quad * 8]);
#pragma unroll
        for (int n = 0; n < 4; ++n)
            bf[n] = *(const short8*)(&Bs[cb][(wn * 64 + n * 16 + fr) * 32 + quad * 8]);
        if (t + 2 < 32) {                        // buf (t+2)%3 last read at t-1 -> safe
            int nb = (t + 2) - ((t + 2) / 3) * 3;
            STAGE((t + 2) * 32, nb);
        }
#pragma unroll
        for (int m = 0; m < MR; ++m)
#pragma unroll
            for (int n = 0; n < 4; ++n)
                acc[m][n] = __builtin_amdgcn_mfma_f32_16x16x32_bf16(af[m], bf[n], acc[m][n], 0, 0, 0);
    }
#pragma unroll
    for (int n = 0; n < 4; ++n) {
        int gc = n0 + wn * 64 + n * 16 + fr;
        float bv = bias[gc];
#pragma unroll
        for (int m = 0; m < MR; ++m) {
#pragma unroll
            for (int r = 0; r < 4; ++r) {
                int gr = m0 + wm * (MR * 16) + m * 16 + quad * 4 + r;
                float val = acc[m][n][r] + bv;
                if (MODE == 1) {
                    outf[(size_t)gr * N + gc] = val;
                } else {
                    int sec = gc >> 10, h = (gc >> 6) & 15, d = gc & 63;
                    int b = gr >> 10, sq = gr & 1023;
                    int bh = b * HH + h;
                    if (sec == 0) {
                        // fold 1/sqrt(D)*log2(e); frag-major q
                        qfrag[(size_t)bh * 65536 + (sq >> 5) * 2048 + (d >> 4) * 512
                              + ((sq & 31) + ((d >> 3) & 1) * 32) * 8 + (d & 7)]
                            = f2bf(val * 0.18033688f);
                    } else {
                        size_t off = ((size_t)bh * NS + PP + sq) * DD + d;
                        if (sec == 1) {
                            present[off] = val;
                            kfrag[(size_t)bh * 131072 + ((PP + sq) >> 5) * 2048 + (d >> 4) * 512
                                  + ((sq & 31) + ((d >> 3) & 1) * 32) * 8 + (d & 7)] = f2bf(val);
                        } else {
                            present[VOFF + off] = val;
                            vfrag[(size_t)bh * 131072 + ((PP + sq) >> 4) * 1024 + (d >> 5) * 512
                                  + ((d & 31) + ((sq >> 3) & 1) * 32) * 8 + (sq & 7)] = f2bf(val);
                        }
                    }
                }
            }
        }
    }
}

// ---- flash attention: zero-LDS loop, frag-major coalesced K/V/Q, independent waves ----
// 128 thr = 2 waves (sp key-parity pair) per 32-q tile. grid = 64 bh x 32 qt = 2048 blocks
// (8 blocks/CU, 16 waves/CU, no barriers in loop). Per 32-key chunk: 8 coalesced 16B loads
// + 4 QK MFMA + in-reg softmax (log2 domain, defer-max) + cvt_pk/permlane P + 4 PV MFMA.
__global__ __launch_bounds__(128, 4) void flash_attn_k(
    const short* __restrict__ qfrag, const short* __restrict__ kfrag,
    const short* __restrict__ vfrag, short* __restrict__ ab)
{
    __shared__ float Of[64 * 32];                // 8 KB merge buffer
    __shared__ float ml[2][32][2];

    int tid = threadIdx.x;
    int sp = tid >> 6, lane = tid & 63;
    int qcol = lane & 31, hi = lane >> 5;

    // XCD-chunked + LPT: xcd = bid&7; within XCD 8 bh; longest q-tiles first
    int bid = blockIdx.x;
    int xcd = bid & 7, idx = bid >> 3;
    int bh = xcd * 8 + (idx & 7);
    int qt = 31 - (idx >> 3);
    int q32 = qt * 32;

    const short* qb_ = qfrag + (size_t)bh * 65536 + qt * 2048 + lane * 8;
    short8 qf[4];
#pragma unroll
    for (int d0 = 0; d0 < 4; ++d0) qf[d0] = *(const short8*)(qb_ + d0 * 512);

    const short* kb = kfrag + (size_t)bh * 131072 + lane * 8;
    const short* vb = vfrag + (size_t)bh * 131072 + lane * 8;

    float m_r = -1e30f, l_r = 0.f;
    floatx16 Oa[2];
#pragma unroll
    for (int dt = 0; dt < 2; ++dt)
#pragma unroll
        for (int r = 0; r < 16; ++r) Oa[dt][r] = 0.f;

    int qa_abs = PP + q32 + qcol;
    int ncha = 33 + qt;                          // 32-key chunks for this q-tile

    for (int c = sp; c < ncha; c += 2) {
        const short* kc = kb + c * 2048;
        const short* vc = vb + c * 2048;         // c16 = 2c -> ks*1024, dt*512
        short8 kf0 = *(const short8*)(kc);
        short8 kf1 = *(const short8*)(kc + 512);
        short8 kf2 = *(const short8*)(kc + 1024);
        short8 kf3 = *(const short8*)(kc + 1536);
        short8 v00 = *(const short8*)(vc);          // ks0 dt0
        short8 v01 = *(const short8*)(vc + 512);    // ks0 dt1
        short8 v10 = *(const short8*)(vc + 1024);   // ks1 dt0
        short8 v11 = *(const short8*)(vc + 1536);   // ks1 dt1
        // ---- S^T[key][q] = K·Q^T (log2 domain) ----
        floatx16 Sa;
#pragma unroll
        for (int r = 0; r < 16; ++r) Sa[r] = 0.f;
        __builtin_amdgcn_s_setprio(1);
        Sa = __builtin_amdgcn_mfma_f32_32x32x16_bf16(kf0, qf[0], Sa, 0, 0, 0);
        Sa = __builtin_amdgcn_mfma_f32_32x32x16_bf16(kf1, qf[1], Sa, 0, 0, 0);
        Sa = __builtin_amdgcn_mfma_f32_32x32x16_bf16(kf2, qf[2], Sa, 0, 0, 0);
        Sa = __builtin_amdgcn_mfma_f32_32x32x16_bf16(kf3, qf[3], Sa, 0, 0, 0);
        __builtin_amdgcn_s_setprio(0);
        // causal mask (near-diagonal chunks only)
        if (c * 32 + 31 > PP + q32) {
#pragma unroll
            for (int r = 0; r < 16; ++r) {
                int ka = c * 32 + (r & 3) + 8 * (r >> 2) + 4 * hi;
                if (ka > qa_abs) Sa[r] = -1e30f;
            }
        }
        // ---- in-register online softmax; defer-max (THR = 8 nats = 11.54 log2) ----
        float mx0 = fmaxf(Sa[0], Sa[1]),  mx1 = fmaxf(Sa[2], Sa[3]);
        float mx2 = fmaxf(Sa[4], Sa[5]),  mx3 = fmaxf(Sa[6], Sa[7]);
        mx0 = fmaxf(mx0, fmaxf(Sa[8], Sa[9]));
        mx1 = fmaxf(mx1, fmaxf(Sa[10], Sa[11]));
        mx2 = fmaxf(mx2, fmaxf(Sa[12], Sa[13]));
        mx3 = fmaxf(mx3, fmaxf(Sa[14], Sa[15]));
        float mx = fmaxf(fmaxf(mx0, mx1), fmaxf(mx2, mx3));
        mx = fmaxf(mx, __shfl_xor(mx, 32, 64));
        if (!__all(mx <= m_r + 11.5416f)) {
            float mnew = fmaxf(m_r, mx);
            float al = exp2f(m_r - mnew);
            l_r *= al;
#pragma unroll
            for (int dt = 0; dt < 2; ++dt)
#pragma unroll
                for (int r = 0; r < 16; ++r) Oa[dt][r] *= al;
            m_r = mnew;
        }
        float s0 = 0.f, s1 = 0.f, s2 = 0.f, s3 = 0.f;
#pragma unroll
        for (int r = 0; r < 16; r += 4) {
            float p0 = exp2f(Sa[r]     - m_r);
            float p1 = exp2f(Sa[r + 1] - m_r);
            float p2 = exp2f(Sa[r + 2] - m_r);
            float p3 = exp2f(Sa[r + 3] - m_r);
            Sa[r] = p0; Sa[r + 1] = p1; Sa[r + 2] = p2; Sa[r + 3] = p3;
            s0 += p0; s1 += p1; s2 += p2; s3 += p3;
        }
        float sum = (s0 + s1) + (s2 + s3);
        sum += __shfl_xor(sum, 32, 64);
        l_r += sum;
        // ---- P -> B-operand frags: cvt_pk + permlane32_swap ----
        short8 pfr[2];
        {
            unsigned w0 = cvtpk(Sa[0],  Sa[1]);
            unsigned w2 = cvtpk(Sa[4],  Sa[5]);
            unsigned w1 = cvtpk(Sa[2],  Sa[3]);
            unsigned w3 = cvtpk(Sa[6],  Sa[7]);
            plswap(w0, w2);
            plswap(w1, w3);
            union { uintx4 u; short8 s; } cv0;
            cv0.u = (uintx4){w0, w1, w2, w3};
            pfr[0] = cv0.s;
            unsigned x0 = cvtpk(Sa[8],  Sa[9]);
            unsigned x2 = cvtpk(Sa[12], Sa[13]);
            unsigned x1 = cvtpk(Sa[10], Sa[11]);
            unsigned x3 = cvtpk(Sa[14], Sa[15]);
            plswap(x0, x2);
            plswap(x1, x3);
            union { uintx4 u; short8 s; } cv1;
            cv1.u = (uintx4){x0, x1, x2, x3};
            pfr[1] = cv1.s;
        }
        // ---- O^T += V^T · P^T ----
        __builtin_amdgcn_s_setprio(1);
        Oa[0] = __builtin_amdgcn_mfma_f32_32x32x16_bf16(v00, pfr[0], Oa[0], 0, 0, 0);
        Oa[0] = __builtin_amdgcn_mfma_f32_32x32x16_bf16(v10, pfr[1], Oa[0], 0, 0, 0);
        Oa[1] = __builtin_amdgcn_mfma_f32_32x32x16_bf16(v01, pfr[0], Oa[1], 0, 0, 0);
        Oa[1] = __builtin_amdgcn_mfma_f32_32x32x16_bf16(v11, pfr[1], Oa[1], 0, 0, 0);
        __builtin_amdgcn_s_setprio(0);
    }

    // ---- merge sp pair: (m,l,O)_sp0 + (m,l,O)_sp1 via LDS ----
    if (hi == 0) {
        ml[sp][qcol][0] = m_r;
        ml[sp][qcol][1] = l_r;
    }
    __syncthreads();
    float m_o = ml[sp ^ 1][qcol][0];
    float l_o = ml[sp ^ 1][qcol][1];
    float M = fmaxf(m_r, m_o);
    float sc = exp2f(m_r - M);
    float l_tot = l_r * sc + l_o * exp2f(m_o - M);
    if (sp == 0) {
#pragma unroll
        for (int dt = 0; dt < 2; ++dt)
#pragma unroll
            for (int r = 0; r < 16; ++r) {
                int d = dt * 32 + (r & 3) + 8 * (r >> 2) + 4 * hi;
                Of[d * 32 + qcol] = Oa[dt][r] * sc;
            }
    }
    __syncthreads();
    if (sp == 1) {
        float inv = 1.f / l_tot;
#pragma unroll
        for (int dt = 0; dt < 2; ++dt)
#pragma unroll
            for (int r = 0; r < 16; ++r) {
                int d = dt * 32 + (r & 3) + 8 * (r >> 2) + 4 * hi;
                Oa[dt][r] = (Of[d * 32 + qcol] + Oa[dt][r] * sc) * inv;
            }
    }
    __syncthreads();
    short* Ot = (short*)Of;                      // [32 q][72 d] bf16
    if (sp == 1) {
#pragma unroll
        for (int dt = 0; dt < 2; ++dt)
#pragma unroll
            for (int r = 0; r < 16; ++r) {
                int d = dt * 32 + (r & 3) + 8 * (r >> 2) + 4 * hi;
                Ot[qcol * 72 + d] = f2bf(Oa[dt][r]);
            }
    }
    __syncthreads();
    // coalesced store: 128 threads x 32B = 32 rows x 128B
    int q = tid >> 2, doff = (tid & 3) * 16;
    int b = bh >> 4, h = bh & 15;
    int qa = q32 + q;
    short* dst = ab + ((size_t)(b * SS + qa)) * EE + h * DD + doff;
    const short* srcr = Ot + q * 72 + doff;
    *(short8*)(dst)     = *(const short8*)(srcr);
    *(short8*)(dst + 8) = *(const short8*)(srcr + 8);
}

extern "C" void kernel_launch(void* const* d_in, const int* in_sizes, int n_in,
                              void* d_out, int out_size, void* d_ws, size_t ws_size,
                              hipStream_t stream) {
    const float* x      = (const float*)d_in[0];
    const float* past   = (const float*)d_in[1];
    const float* w_attn = (const float*)d_in[2];
    const float* b_attn = (const float*)d_in[3];
    const float* w_proj = (const float*)d_in[4];
    const float* b_proj = (const float*)d_in[5];
    float* out = (float*)d_out;
    float* present = out + (size_t)BB * SS * EE;

    // workspace (bf16 staging), ~67 MiB total
    short* ws    = (short*)d_ws;
    short* xb    = ws;                 // [4096][1024]              4,194,304
    short* wab   = xb    + 4194304;    // w_attn^T [3072][1024]     3,145,728
    short* wpb   = wab   + 3145728;    // w_proj^T [1024][1024]     1,048,576
    short* qfrag = wpb   + 1048576;    // q frag-major, prescaled   4,194,304
    short* kfrag = qfrag + 4194304;    // K frag-major [bh][c32]..  8,388,608
    short* vfrag = kfrag + 8388608;    // V frag-major [bh][c16]..  8,388,608
    short* ab    = vfrag + 8388608;    // attn out [B,S,E]          4,194,304

    cvt_copy_k<<<6144, 256, 0, stream>>>(x, past, xb, kfrag, vfrag, present);
    wtrans_k<<<1024, 256, 0, stream>>>(w_attn, w_proj, wab, wpb);
    gemm_bt_k<0, 128><<<dim3(32, 24), 256, 0, stream>>>(xb, wab, b_attn, nullptr,
                                                        qfrag, kfrag, vfrag, present, E3);
    flash_attn_k<<<2048, 128, 0, stream>>>(qfrag, kfrag, vfrag, ab);
    gemm_bt_k<1, 64><<<dim3(32, 16), 256, 0, stream>>>(ab, wpb, b_proj, out,
                                                       nullptr, nullptr, nullptr, nullptr, EE);
}